// Round 4
// baseline (416.840 us; speedup 1.0000x reference)
//
#include <hip/hip_runtime.h>
#include <hip/hip_bf16.h>

#define N_NODES 50000
#define N_EDGES 600000
#define D 128
#define BS 512
#define L 10
#define MAXS (BS*L + BS)   // 5632 max needed slots
#define NOUT 49999
#define NTILES 3125        // ceil(49999/16)

typedef __attribute__((ext_vector_type(8))) short bf16x8;
typedef __attribute__((ext_vector_type(4))) float f32x4;

__device__ __forceinline__ unsigned short f2bf(float f){
  union { float f; unsigned int i; } v; v.f = f;
  unsigned int i = v.i;
  return (unsigned short)((i + 0x7fffu + ((i >> 16) & 1u)) >> 16);
}
__device__ __forceinline__ float sigm(float x){ return 1.f/(1.f+__expf(-x)); }
__device__ __forceinline__ float tanh_f(float x){
  x = fminf(fmaxf(x, -15.f), 15.f);
  float e = __expf(2.f*x);
  return (e-1.f)/(e+1.f);
}
__device__ __forceinline__ bf16x8 cvt8(const float* __restrict__ p){
  bf16x8 r;
  #pragma unroll
  for (int j=0;j<8;j++) r[j] = (short)f2bf(p[j]);
  return r;
}

// ---- K1a: mark needed nodes ----
__global__ void k_mark(const int* __restrict__ seq, const int* __restrict__ user,
                       const int* __restrict__ item_num, int* __restrict__ map){
  int i = blockIdx.x*256 + threadIdx.x;
  if (i < BS*L) { map[seq[i]] = 1; }
  else if (i < BS*L + BS) { map[user[i - BS*L] + item_num[0]] = 1; }
}

// ---- K1b: compact to slots; map[n] = slot+2 (0 = unneeded) ----
__global__ void k_compact(int* __restrict__ map, int* __restrict__ invmap, int* __restrict__ counters){
  int n = blockIdx.x*256 + threadIdx.x;
  if (n < N_NODES && map[n]) {
    int s = atomicAdd(&counters[0], 1);
    map[n] = s + 2;
    invmap[s] = n;
  }
}

// ---- K2a: count edges per needed slot ----
__global__ void k_count(const int* __restrict__ edst, const int* __restrict__ map,
                        int* __restrict__ scount){
  for (int e = blockIdx.x*blockDim.x + threadIdx.x; e < N_EDGES; e += gridDim.x*blockDim.x){
    int mv = map[edst[e]];
    if (mv >= 2) atomicAdd(&scount[mv - 2], 1);
  }
}

// ---- K2b: exclusive scan of scount -> soffs (1 block, 1024 thr, 6/thread) ----
__global__ void k_scan(const int* __restrict__ scount, int* __restrict__ soffs){
  __shared__ int part[1024];
  int t = threadIdx.x;
  int base = t*6;
  int loc[6]; int sum = 0;
  #pragma unroll
  for (int j=0;j<6;j++){ int idx = base+j; int c = (idx < MAXS) ? scount[idx] : 0; loc[j]=sum; sum+=c; }
  part[t] = sum; __syncthreads();
  for (int off=1; off<1024; off<<=1){
    int v = (t>=off) ? part[t-off] : 0; __syncthreads();
    part[t] += v; __syncthreads();
  }
  int ex = (t>0) ? part[t-1] : 0;
  #pragma unroll
  for (int j=0;j<6;j++){ int idx = base+j; if (idx < MAXS) soffs[idx] = ex + loc[j]; }
}

// ---- K2c: scatter edge sources into per-slot buckets ----
__global__ void k_scatter(const int* __restrict__ esrc, const int* __restrict__ edst,
                          const int* __restrict__ map, const int* __restrict__ soffs,
                          int* __restrict__ cursor, int* __restrict__ bucket){
  for (int e = blockIdx.x*blockDim.x + threadIdx.x; e < N_EDGES; e += gridDim.x*blockDim.x){
    int mv = map[edst[e]];
    if (mv >= 2){
      int slot = mv - 2;
      int pos = soffs[slot] + atomicAdd(&cursor[slot], 1);
      bucket[pos] = esrc[e];
    }
  }
}

// ---- K2d: per-slot gather-sum -> neigh = agg/max(deg,1) ----
__global__ void k_neigh(const float* __restrict__ v2e, const int* __restrict__ bucket,
                        const int* __restrict__ soffs, const int* __restrict__ scount,
                        const int* __restrict__ counters, float* __restrict__ neigh){
  int s = blockIdx.x; int t = threadIdx.x;
  if (s >= counters[0]) return;
  int cnt = scount[s]; int off = soffs[s];
  float acc = 0.f;
  for (int j=0;j<cnt;j++){
    int src = bucket[off+j];
    acc += v2e[(size_t)src*D + t];
  }
  neigh[(size_t)s*D + t] = acc / fmaxf((float)cnt, 1.0f);
}

// ---- K3: h1 for needed slots only (8 slots/block) ----
#define SL8 8
__global__ __launch_bounds__(128) void k_h1(const float* __restrict__ v2e,
                     const float* __restrict__ neigh, const int* __restrict__ invmap,
                     const int* __restrict__ counters, const float* __restrict__ Wself,
                     const float* __restrict__ Wneigh, const float* __restrict__ bsage,
                     float* __restrict__ h1c){
  __shared__ float vv[SL8][D];
  __shared__ float nn[SL8][D];
  int t = threadIdx.x;
  int nslots = counters[0];
  int sb = blockIdx.x*SL8;
  for (int i=0;i<SL8;i++){
    int s = sb+i;
    if (s < nslots){
      int node = invmap[s];
      vv[i][t] = v2e[(size_t)node*D + t];
      nn[i][t] = neigh[(size_t)s*D + t];
    }
  }
  __syncthreads();
  float bias = bsage[t];
  float acc[SL8];
  #pragma unroll
  for (int i=0;i<SL8;i++) acc[i] = bias;
  for (int k=0;k<D;k++){
    float ws = Wself[k*D + t];
    float wn = Wneigh[k*D + t];
    #pragma unroll
    for (int i=0;i<SL8;i++) acc[i] += vv[i][k]*ws + nn[i][k]*wn;
  }
  for (int i=0;i<SL8;i++){
    int s = sb+i;
    if (s < nslots) h1c[(size_t)s*D + t] = fmaxf(acc[i], 0.f);
  }
}

// ---- K4: session/attention block. 1 block per b, 640 thr = wave per l ----
__global__ __launch_bounds__(640) void k_sess(
    const int* __restrict__ user, const int* __restrict__ seq, const int* __restrict__ mask,
    const int* __restrict__ pos_idx, const int* __restrict__ item_num, const int* __restrict__ map,
    const float* __restrict__ h1c, const float* __restrict__ v2e,
    const float* __restrict__ pos_w,
    const float* __restrict__ w1, const float* __restrict__ w2,
    const float* __restrict__ glu1_w, const float* __restrict__ glu1_b,
    const float* __restrict__ glu2_w,
    const float* __restrict__ w3, const float* __restrict__ w4,
    const float* __restrict__ glu3_w, const float* __restrict__ glu3_b,
    const float* __restrict__ glu4_w,
    const float* __restrict__ wc_w, const float* __restrict__ wc_b,
    unsigned short* __restrict__ seqemb){
  __shared__ float ie[L][D], pe[L][D], nh1[L][D], nh2[L][D];
  __shared__ float ue[D], avg[D], g2[D], g4[D];
  __shared__ float beta1[L], beta2[L];
  __shared__ float mS[L];
  __shared__ float red[10];
  __shared__ float alphaS;
  int b = blockIdx.x;
  int tid = threadIdx.x;
  int w = tid >> 6, lane = tid & 63;
  int d0 = 2*lane, d1 = 2*lane + 1;

  { // P0: gather item_e, pos_e, user_e
    int l = w;
    int node = seq[b*L + l];
    int slot = map[node] - 2;
    ie[l][d0] = 0.5f*(h1c[(size_t)slot*D + d0] + v2e[(size_t)node*D + d0]);
    ie[l][d1] = 0.5f*(h1c[(size_t)slot*D + d1] + v2e[(size_t)node*D + d1]);
    int p = pos_idx[b*L + l];
    pe[l][d0] = pos_w[p*D + d0];
    pe[l][d1] = pos_w[p*D + d1];
    if (lane == 0) mS[l] = (float)mask[b*L + l];
    if (l == 0){
      int unode = user[b] + item_num[0];
      int uslot = map[unode] - 2;
      ue[d0] = 0.5f*(h1c[(size_t)uslot*D + d0] + v2e[(size_t)unode*D + d0]);
      ue[d1] = 0.5f*(h1c[(size_t)uslot*D + d1] + v2e[(size_t)unode*D + d1]);
    }
  }
  __syncthreads();
  if (tid < D){ // P1: avg
    float msum = 0.f, av = 0.f;
    #pragma unroll
    for (int l=0;l<L;l++){ msum += mS[l]; av += ie[l][tid]*mS[l]; }
    avg[tid] = av / msum;
  }
  __syncthreads();
  if (tid < D){ // P2: g2 = avg @ glu2_w
    float a = 0.f;
    for (int k=0;k<D;k++) a += avg[k]*glu2_w[k*D + tid];
    g2[tid] = a;
  } else if (tid < 2*D){ // g4 = user_e @ glu4_w
    int t2 = tid - D; float a = 0.f;
    for (int k=0;k<D;k++) a += ue[k]*glu4_w[k*D + t2];
    g4[t2] = a;
  }
  __syncthreads();
  { // P3: nh1 = tanh([pe|ie]@w1), nh2 = tanh(ie@w3)
    int l = w;
    float a0=0.f, a1=0.f, c0=0.f, c1=0.f;
    for (int k=0;k<D;k++){
      float pk = pe[l][k], ik = ie[l][k];
      a0 += pk*w1[k*D + d0]       + ik*w1[(D+k)*D + d0];
      a1 += pk*w1[k*D + d1]       + ik*w1[(D+k)*D + d1];
      c0 += ik*w3[k*D + d0];
      c1 += ik*w3[k*D + d1];
    }
    nh1[l][d0] = tanh_f(a0); nh1[l][d1] = tanh_f(a1);
    nh2[l][d0] = tanh_f(c0); nh2[l][d1] = tanh_f(c1);
  }
  __syncthreads();
  { // P4: GLU + beta reductions
    int l = w;
    float a0 = glu1_b[d0] + g2[d0], a1 = glu1_b[d1] + g2[d1];
    float c0 = glu3_b[d0] + g4[d0], c1 = glu3_b[d1] + g4[d1];
    for (int k=0;k<D;k++){
      float n1 = nh1[l][k], n2 = nh2[l][k];
      a0 += n1*glu1_w[k*D + d0]; a1 += n1*glu1_w[k*D + d1];
      c0 += n2*glu3_w[k*D + d0]; c1 += n2*glu3_w[k*D + d1];
    }
    float s0 = sigm(a0)*w2[d0] + sigm(a1)*w2[d1];
    float s1 = sigm(c0)*w4[d0] + sigm(c1)*w4[d1];
    #pragma unroll
    for (int off=32; off; off>>=1){ s0 += __shfl_down(s0, off, 64); s1 += __shfl_down(s1, off, 64); }
    if (lane == 0){ beta1[l] = s0*mS[l]; beta2[l] = s1*mS[l]; }
  }
  __syncthreads();
  // P5: sess vectors, alpha, final seq_emb
  float sv = 0.f, su = 0.f, partial = 0.f;
  if (tid < D){
    #pragma unroll
    for (int l=0;l<L;l++){ sv += beta1[l]*ie[l][tid]; su += beta2[l]*ie[l][tid]; }
    partial = sv*wc_w[tid] + su*wc_w[D + tid];
  }
  #pragma unroll
  for (int off=32; off; off>>=1) partial += __shfl_down(partial, off, 64);
  if (lane == 0) red[w] = partial;
  __syncthreads();
  if (tid == 0) alphaS = sigm(red[0] + red[1] + wc_b[0]);
  __syncthreads();
  if (tid < D){
    float al = alphaS;
    seqemb[b*D + tid] = f2bf(ue[tid] + al*sv + (1.f - al)*su);
  }
}

// ---- K5: scores = seq_emb(512x128) @ v2e[1:]^T (49999x128), MFMA bf16, f32 out ----
__global__ __launch_bounds__(256) void k_scores(const unsigned short* __restrict__ A,
                                                const float* __restrict__ v2e,
                                                float* __restrict__ out){
  int tid = threadIdx.x;
  int wv = tid >> 6, lane = tid & 63;
  int q = lane >> 4, r = lane & 15;
  int ntile = blockIdx.x*4 + wv;
  int n = ntile*16 + r;
  bool valid = (ntile < NTILES) && (n < NOUT);
  int brow = valid ? (1 + n) : 0;
  const float* Bf = v2e + (size_t)brow*D + q*8;
  bf16x8 b0 = cvt8(Bf);
  bf16x8 b1 = cvt8(Bf + 32);
  bf16x8 b2 = cvt8(Bf + 64);
  bf16x8 b3 = cvt8(Bf + 96);
  #pragma unroll 4
  for (int mt=0; mt<32; mt++){
    const bf16x8* Ap = (const bf16x8*)(A + (size_t)(mt*16 + r)*D + q*8);
    f32x4 acc = {0.f, 0.f, 0.f, 0.f};
    acc = __builtin_amdgcn_mfma_f32_16x16x32_bf16(Ap[0],  b0, acc, 0, 0, 0);
    acc = __builtin_amdgcn_mfma_f32_16x16x32_bf16(Ap[4],  b1, acc, 0, 0, 0);
    acc = __builtin_amdgcn_mfma_f32_16x16x32_bf16(Ap[8],  b2, acc, 0, 0, 0);
    acc = __builtin_amdgcn_mfma_f32_16x16x32_bf16(Ap[12], b3, acc, 0, 0, 0);
    if (valid){
      size_t base = (size_t)(mt*16 + q*4)*NOUT + n;
      out[base]          = acc[0];
      out[base +   NOUT] = acc[1];
      out[base + 2*NOUT] = acc[2];
      out[base + 3*NOUT] = acc[3];
    }
  }
}

extern "C" void kernel_launch(void* const* d_in, const int* in_sizes, int n_in,
                              void* d_out, int out_size, void* d_ws, size_t ws_size,
                              hipStream_t stream) {
  const int* user     = (const int*)d_in[0];
  const int* seq      = (const int*)d_in[1];
  const int* maskp    = (const int*)d_in[2];
  const int* pos_idx  = (const int*)d_in[4];
  const int* esrc     = (const int*)d_in[5];
  const int* edst     = (const int*)d_in[6];
  const int* item_num = (const int*)d_in[7];
  const float* v2e    = (const float*)d_in[8];
  const float* pos_w  = (const float*)d_in[9];
  const float* Wself  = (const float*)d_in[10];
  const float* Wneigh = (const float*)d_in[11];
  const float* bsage  = (const float*)d_in[12];
  const float* w1     = (const float*)d_in[13];
  const float* w2     = (const float*)d_in[14];
  const float* glu1_w = (const float*)d_in[15];
  const float* glu1_b = (const float*)d_in[16];
  const float* glu2_w = (const float*)d_in[17];
  const float* w3     = (const float*)d_in[18];
  const float* w4     = (const float*)d_in[19];
  const float* glu3_w = (const float*)d_in[20];
  const float* glu3_b = (const float*)d_in[21];
  const float* glu4_w = (const float*)d_in[22];
  const float* wc_w   = (const float*)d_in[23];
  const float* wc_b   = (const float*)d_in[24];
  float* out = (float*)d_out;
  char* ws = (char*)d_ws;

  size_t off = 0;
  auto take = [&](size_t n){ size_t o = off; off += (n + 255) & ~(size_t)255; return o; };
  size_t o_map    = take((size_t)N_NODES*4);
  size_t o_cnt    = take(16);
  size_t o_scount = take((size_t)MAXS*4);
  size_t o_cursor = take((size_t)MAXS*4);
  size_t zero_end = off;
  size_t o_soffs  = take((size_t)MAXS*4);
  size_t o_invmap = take((size_t)MAXS*4);
  size_t o_bucket = take((size_t)N_EDGES*4);
  size_t o_neigh  = take((size_t)MAXS*D*4);
  size_t o_h1c    = take((size_t)MAXS*D*4);
  size_t o_semb   = take((size_t)BS*D*2);

  int* map      = (int*)(ws + o_map);
  int* counters = (int*)(ws + o_cnt);
  int* scount   = (int*)(ws + o_scount);
  int* cursor   = (int*)(ws + o_cursor);
  int* soffs    = (int*)(ws + o_soffs);
  int* invmap   = (int*)(ws + o_invmap);
  int* bucket   = (int*)(ws + o_bucket);
  float* neigh  = (float*)(ws + o_neigh);
  float* h1c    = (float*)(ws + o_h1c);
  unsigned short* semb = (unsigned short*)(ws + o_semb);

  hipMemsetAsync(ws, 0, zero_end, stream);

  k_mark<<<(MAXS + 255)/256, 256, 0, stream>>>(seq, user, item_num, map);
  k_compact<<<(N_NODES + 255)/256, 256, 0, stream>>>(map, invmap, counters);
  k_count<<<512, 256, 0, stream>>>(edst, map, scount);
  k_scan<<<1, 1024, 0, stream>>>(scount, soffs);
  k_scatter<<<512, 256, 0, stream>>>(esrc, edst, map, soffs, cursor, bucket);
  k_neigh<<<MAXS, D, 0, stream>>>(v2e, bucket, soffs, scount, counters, neigh);
  k_h1<<<(MAXS + SL8 - 1)/SL8, D, 0, stream>>>(v2e, neigh, invmap, counters, Wself, Wneigh, bsage, h1c);
  k_sess<<<BS, 640, 0, stream>>>(user, seq, maskp, pos_idx, item_num, map, h1c, v2e, pos_w,
                                 w1, w2, glu1_w, glu1_b, glu2_w, w3, w4, glu3_w, glu3_b, glu4_w,
                                 wc_w, wc_b, semb);
  k_scores<<<(NTILES + 3)/4, 256, 0, stream>>>(semb, v2e, out);
}

// Round 5
// 343.682 us; speedup vs baseline: 1.2129x; 1.2129x over previous
//
#include <hip/hip_runtime.h>
#include <hip/hip_bf16.h>

#define N_NODES 50000
#define N_EDGES 600000
#define D 128
#define BS 512
#define L 10
#define MAXS (BS*L + BS)   // 5632 max needed slots
#define NOUT 49999
#define NTILES 3125        // ceil(49999/16)

// wT element offsets (bf16, (n,k) layout)
#define W1T 0        // 128 x 256
#define W3T 32768    // 128 x 128
#define G1T 49152
#define G2T 65536
#define G3T 81920
#define G4T 98304
#define WT_ELEMS 114688

typedef __attribute__((ext_vector_type(8))) short bf16x8;
typedef __attribute__((ext_vector_type(4))) float f32x4;

__device__ __forceinline__ unsigned short f2bf(float f){
  union { float f; unsigned int i; } v; v.f = f;
  unsigned int i = v.i;
  return (unsigned short)((i + 0x7fffu + ((i >> 16) & 1u)) >> 16);
}
__device__ __forceinline__ float sigm(float x){ return 1.f/(1.f+__expf(-x)); }
__device__ __forceinline__ float tanh_f(float x){
  x = fminf(fmaxf(x, -15.f), 15.f);
  float e = __expf(2.f*x);
  return (e-1.f)/(e+1.f);
}

// ---- K1a: mark needed nodes ----
__global__ void k_mark(const int* __restrict__ seq, const int* __restrict__ user,
                       const int* __restrict__ item_num, int* __restrict__ map){
  int i = blockIdx.x*256 + threadIdx.x;
  if (i < BS*L) { map[seq[i]] = 1; }
  else if (i < BS*L + BS) { map[user[i - BS*L] + item_num[0]] = 1; }
}

// ---- K1b: compact to slots; map[n] = slot+2 (0 = unneeded) ----
__global__ void k_compact(int* __restrict__ map, int* __restrict__ invmap, int* __restrict__ counters){
  int n = blockIdx.x*256 + threadIdx.x;
  if (n < N_NODES && map[n]) {
    int s = atomicAdd(&counters[0], 1);
    map[n] = s + 2;
    invmap[s] = n;
  }
}

// ---- K2a: count edges per needed slot ----
__global__ void k_count(const int* __restrict__ edst, const int* __restrict__ map,
                        int* __restrict__ scount){
  for (int e = blockIdx.x*blockDim.x + threadIdx.x; e < N_EDGES; e += gridDim.x*blockDim.x){
    int mv = map[edst[e]];
    if (mv >= 2) atomicAdd(&scount[mv - 2], 1);
  }
}

// ---- K2b: exclusive scan of scount -> soffs ----
__global__ void k_scan(const int* __restrict__ scount, int* __restrict__ soffs){
  __shared__ int part[1024];
  int t = threadIdx.x;
  int base = t*6;
  int loc[6]; int sum = 0;
  #pragma unroll
  for (int j=0;j<6;j++){ int idx = base+j; int c = (idx < MAXS) ? scount[idx] : 0; loc[j]=sum; sum+=c; }
  part[t] = sum; __syncthreads();
  for (int off=1; off<1024; off<<=1){
    int v = (t>=off) ? part[t-off] : 0; __syncthreads();
    part[t] += v; __syncthreads();
  }
  int ex = (t>0) ? part[t-1] : 0;
  #pragma unroll
  for (int j=0;j<6;j++){ int idx = base+j; if (idx < MAXS) soffs[idx] = ex + loc[j]; }
}

// ---- K2c: scatter edge sources into per-slot buckets ----
__global__ void k_scatter(const int* __restrict__ esrc, const int* __restrict__ edst,
                          const int* __restrict__ map, const int* __restrict__ soffs,
                          int* __restrict__ cursor, int* __restrict__ bucket){
  for (int e = blockIdx.x*blockDim.x + threadIdx.x; e < N_EDGES; e += gridDim.x*blockDim.x){
    int mv = map[edst[e]];
    if (mv >= 2){
      int slot = mv - 2;
      int pos = soffs[slot] + atomicAdd(&cursor[slot], 1);
      bucket[pos] = esrc[e];
    }
  }
}

// ---- K2d: per-slot gather-sum -> neigh = agg/max(deg,1) ----
__global__ void k_neigh(const float* __restrict__ v2e, const int* __restrict__ bucket,
                        const int* __restrict__ soffs, const int* __restrict__ scount,
                        const int* __restrict__ counters, float* __restrict__ neigh){
  int s = blockIdx.x; int t = threadIdx.x;
  if (s >= counters[0]) return;
  int cnt = scount[s]; int off = soffs[s];
  float acc = 0.f;
  for (int j=0;j<cnt;j++){
    int src = bucket[off+j];
    acc += v2e[(size_t)src*D + t];
  }
  neigh[(size_t)s*D + t] = acc / fmaxf((float)cnt, 1.0f);
}

// ---- K3: h1 for needed slots only (8 slots/block) ----
#define SL8 8
__global__ __launch_bounds__(128) void k_h1(const float* __restrict__ v2e,
                     const float* __restrict__ neigh, const int* __restrict__ invmap,
                     const int* __restrict__ counters, const float* __restrict__ Wself,
                     const float* __restrict__ Wneigh, const float* __restrict__ bsage,
                     float* __restrict__ h1c){
  __shared__ float vv[SL8][D];
  __shared__ float nn[SL8][D];
  int t = threadIdx.x;
  int nslots = counters[0];
  int sb = blockIdx.x*SL8;
  for (int i=0;i<SL8;i++){
    int s = sb+i;
    if (s < nslots){
      int node = invmap[s];
      vv[i][t] = v2e[(size_t)node*D + t];
      nn[i][t] = neigh[(size_t)s*D + t];
    }
  }
  __syncthreads();
  float bias = bsage[t];
  float acc[SL8];
  #pragma unroll
  for (int i=0;i<SL8;i++) acc[i] = bias;
  for (int k=0;k<D;k++){
    float ws = Wself[k*D + t];
    float wn = Wneigh[k*D + t];
    #pragma unroll
    for (int i=0;i<SL8;i++) acc[i] += vv[i][k]*ws + nn[i][k]*wn;
  }
  for (int i=0;i<SL8;i++){
    int s = sb+i;
    if (s < nslots) h1c[(size_t)s*D + t] = fmaxf(acc[i], 0.f);
  }
}

// ---- K_prep: transpose+cvt weights to bf16 (n,k) layout ----
// grid: 448 blocks x 256. blocks 0..127: w1 (256x128). 128..447: 5 matrices of 128x128.
__global__ __launch_bounds__(256) void k_prep(const float* __restrict__ w1,
    const float* __restrict__ w3, const float* __restrict__ g1,
    const float* __restrict__ g2, const float* __restrict__ g3,
    const float* __restrict__ g4, unsigned short* __restrict__ wT){
  int bid = blockIdx.x, tid = threadIdx.x;
  if (bid < 128){
    int e = bid*256 + tid;          // linear over source w1 (256k x 128n)
    int k = e >> 7, n = e & 127;
    wT[W1T + n*256 + k] = f2bf(w1[e]);
  } else {
    int mm = (bid - 128) >> 6;      // 0..4
    int e = ((bid - 128) & 63)*256 + tid;  // linear over 128x128 source
    int k = e >> 7, n = e & 127;
    const float* src = (mm==0)? w3 : (mm==1)? g1 : (mm==2)? g2 : (mm==3)? g3 : g4;
    int dst = (mm==0)? W3T : (mm==1)? G1T : (mm==2)? G2T : (mm==3)? G3T : G4T;
    wT[dst + n*128 + k] = f2bf(src[e]);
  }
}

// ---- K4a: gather ie/pe/ue/avg; build bf16 A-matrices ----
__global__ __launch_bounds__(128) void k4a(const int* __restrict__ user, const int* __restrict__ seq,
    const int* __restrict__ mask, const int* __restrict__ pos_idx, const int* __restrict__ item_num,
    const int* __restrict__ map, const float* __restrict__ h1c, const float* __restrict__ v2e,
    const float* __restrict__ pos_w, float* __restrict__ ie, float* __restrict__ ue,
    unsigned short* __restrict__ Xcat, unsigned short* __restrict__ AU){
  int b = blockIdx.x, t = threadIdx.x;
  float av = 0.f, msum = 0.f;
  for (int l=0;l<L;l++){
    int node = seq[b*L+l];
    int slot = map[node]-2;
    float v = 0.5f*(h1c[(size_t)slot*D+t] + v2e[(size_t)node*D+t]);
    ie[(size_t)(b*L+l)*D+t] = v;
    Xcat[(size_t)(b*L+l)*256 + 128 + t] = f2bf(v);
    int p = pos_idx[b*L+l];
    Xcat[(size_t)(b*L+l)*256 + t] = f2bf(pos_w[(size_t)p*D+t]);
    float m = (float)mask[b*L+l];
    av += v*m; msum += m;
  }
  AU[(size_t)b*D+t] = f2bf(av/msum);
  int unode = user[b]+item_num[0];
  int uslot = map[unode]-2;
  float uv = 0.5f*(h1c[(size_t)uslot*D+t] + v2e[(size_t)unode*D+t]);
  ue[(size_t)b*D+t] = uv;
  AU[(size_t)(512+b)*D+t] = f2bf(uv);
}

// ---- K4b: nh1 = tanh(Xcat @ w1), nh2 = tanh(ie @ w3) via MFMA ----
// grid 320 (m-tiles of 5120 rows), 256 thr (4 waves).
__global__ __launch_bounds__(256) void k4b(const unsigned short* __restrict__ Xcat,
    const unsigned short* __restrict__ wT,
    unsigned short* __restrict__ nh1, unsigned short* __restrict__ nh2){
  int mt = blockIdx.x;
  int wv = threadIdx.x>>6, lane = threadIdx.x&63;
  int r = lane&15, q = lane>>4;
  const bf16x8* Arow = (const bf16x8*)(Xcat + (size_t)(mt*16+r)*256 + q*8);
  bf16x8 a[8];
  #pragma unroll
  for (int kf=0;kf<8;kf++) a[kf] = Arow[kf*4];   // +32 elems per kf
  #pragma unroll
  for (int i=0;i<2;i++){   // nh1, K=256
    int nt = wv + 4*i;
    const bf16x8* Brow = (const bf16x8*)(wT + W1T + (size_t)(nt*16+r)*256 + q*8);
    f32x4 acc = {0.f,0.f,0.f,0.f};
    #pragma unroll
    for (int kf=0;kf<8;kf++)
      acc = __builtin_amdgcn_mfma_f32_16x16x32_bf16(a[kf], Brow[kf*4], acc, 0,0,0);
    #pragma unroll
    for (int g=0; g<4; g++)
      nh1[(size_t)(mt*16 + q*4 + g)*128 + nt*16 + r] = f2bf(tanh_f(acc[g]));
  }
  #pragma unroll
  for (int i=0;i<2;i++){   // nh2, K=128 (ie = Xcat cols 128..255 -> a[4..7])
    int nt = wv + 4*i;
    const bf16x8* Brow = (const bf16x8*)(wT + W3T + (size_t)(nt*16+r)*128 + q*8);
    f32x4 acc = {0.f,0.f,0.f,0.f};
    #pragma unroll
    for (int kf=0;kf<4;kf++)
      acc = __builtin_amdgcn_mfma_f32_16x16x32_bf16(a[4+kf], Brow[kf*4], acc, 0,0,0);
    #pragma unroll
    for (int g=0; g<4; g++)
      nh2[(size_t)(mt*16 + q*4 + g)*128 + nt*16 + r] = f2bf(tanh_f(acc[g]));
  }
}

// ---- K4c: g24 = [avg;ue](1024x128) @ [glu2|glu4](128x128) ----
__global__ __launch_bounds__(256) void k4c(const unsigned short* __restrict__ AU,
    const unsigned short* __restrict__ wT, float* __restrict__ g24){
  int mt = blockIdx.x;  // 0..63
  int wv = threadIdx.x>>6, lane = threadIdx.x&63;
  int r = lane&15, q = lane>>4;
  const unsigned short* Bbase = wT + ((mt*16 >= 512) ? G4T : G2T);
  const bf16x8* Arow = (const bf16x8*)(AU + (size_t)(mt*16+r)*128 + q*8);
  bf16x8 a[4];
  #pragma unroll
  for (int kf=0;kf<4;kf++) a[kf] = Arow[kf*4];
  #pragma unroll
  for (int i=0;i<2;i++){
    int nt = wv + 4*i;
    const bf16x8* Brow = (const bf16x8*)(Bbase + (size_t)(nt*16+r)*128 + q*8);
    f32x4 acc = {0.f,0.f,0.f,0.f};
    #pragma unroll
    for (int kf=0;kf<4;kf++)
      acc = __builtin_amdgcn_mfma_f32_16x16x32_bf16(a[kf], Brow[kf*4], acc, 0,0,0);
    #pragma unroll
    for (int g=0; g<4; g++)
      g24[(size_t)(mt*16 + q*4 + g)*128 + nt*16 + r] = acc[g];
  }
}

// ---- K4d: beta = (sigmoid(nh@glu + b + g) @ w) per row, fused ----
// grid 320 (m-tiles), 256 thr.
__global__ __launch_bounds__(256) void k4d(const unsigned short* __restrict__ nh1,
    const unsigned short* __restrict__ nh2, const unsigned short* __restrict__ wT,
    const float* __restrict__ glu1_b, const float* __restrict__ glu3_b,
    const float* __restrict__ g24, const float* __restrict__ w2, const float* __restrict__ w4,
    float* __restrict__ beta1, float* __restrict__ beta2){
  __shared__ float sb[4][2][16];
  int mt = blockIdx.x;
  int wv = threadIdx.x>>6, lane = threadIdx.x&63;
  int r = lane&15, q = lane>>4;
  int bidx[4];
  #pragma unroll
  for (int g=0; g<4; g++) bidx[g] = (mt*16 + q*4 + g)/10;
  const bf16x8* A1 = (const bf16x8*)(nh1 + (size_t)(mt*16+r)*128 + q*8);
  const bf16x8* A2 = (const bf16x8*)(nh2 + (size_t)(mt*16+r)*128 + q*8);
  bf16x8 a1[4], a2[4];
  #pragma unroll
  for (int kf=0;kf<4;kf++){ a1[kf] = A1[kf*4]; a2[kf] = A2[kf*4]; }
  float accum0[4] = {0.f,0.f,0.f,0.f};
  float accum1[4] = {0.f,0.f,0.f,0.f};
  #pragma unroll
  for (int i=0;i<2;i++){
    int nt = wv + 4*i;
    int col = nt*16 + r;
    {
      const bf16x8* Brow = (const bf16x8*)(wT + G1T + (size_t)col*128 + q*8);
      f32x4 acc = {0.f,0.f,0.f,0.f};
      #pragma unroll
      for (int kf=0;kf<4;kf++)
        acc = __builtin_amdgcn_mfma_f32_16x16x32_bf16(a1[kf], Brow[kf*4], acc, 0,0,0);
      float gb = glu1_b[col], wc = w2[col];
      #pragma unroll
      for (int g=0; g<4; g++){
        float S = acc[g] + gb + g24[(size_t)bidx[g]*128 + col];
        accum0[g] += sigm(S)*wc;
      }
    }
    {
      const bf16x8* Brow = (const bf16x8*)(wT + G3T + (size_t)col*128 + q*8);
      f32x4 acc = {0.f,0.f,0.f,0.f};
      #pragma unroll
      for (int kf=0;kf<4;kf++)
        acc = __builtin_amdgcn_mfma_f32_16x16x32_bf16(a2[kf], Brow[kf*4], acc, 0,0,0);
      float gb = glu3_b[col], wc = w4[col];
      #pragma unroll
      for (int g=0; g<4; g++){
        float S = acc[g] + gb + g24[(size_t)(512 + bidx[g])*128 + col];
        accum1[g] += sigm(S)*wc;
      }
    }
  }
  #pragma unroll
  for (int g=0; g<4; g++){
    float v0 = accum0[g], v1 = accum1[g];
    v0 += __shfl_xor(v0,1,64); v0 += __shfl_xor(v0,2,64); v0 += __shfl_xor(v0,4,64); v0 += __shfl_xor(v0,8,64);
    v1 += __shfl_xor(v1,1,64); v1 += __shfl_xor(v1,2,64); v1 += __shfl_xor(v1,4,64); v1 += __shfl_xor(v1,8,64);
    accum0[g] = v0; accum1[g] = v1;
  }
  if (r == 0){
    #pragma unroll
    for (int g=0; g<4; g++){
      sb[wv][0][q*4+g] = accum0[g];
      sb[wv][1][q*4+g] = accum1[g];
    }
  }
  __syncthreads();
  if (threadIdx.x < 32){
    int m = threadIdx.x>>4, row = threadIdx.x&15;
    float s = sb[0][m][row]+sb[1][m][row]+sb[2][m][row]+sb[3][m][row];
    if (m) beta2[mt*16+row] = s; else beta1[mt*16+row] = s;
  }
}

// ---- K4e: sess vectors, alpha, seq_emb -> bf16 ----
__global__ __launch_bounds__(128) void k4e(const int* __restrict__ mask,
    const float* __restrict__ beta1, const float* __restrict__ beta2,
    const float* __restrict__ ie, const float* __restrict__ ue,
    const float* __restrict__ wc_w, const float* __restrict__ wc_b,
    unsigned short* __restrict__ semb){
  __shared__ float red[2];
  __shared__ float alphaS;
  int b = blockIdx.x, t = threadIdx.x;
  float sv = 0.f, su = 0.f;
  #pragma unroll
  for (int l=0;l<L;l++){
    float m = (float)mask[b*L+l];
    float b1 = beta1[b*L+l]*m, b2 = beta2[b*L+l]*m;
    float v = ie[(size_t)(b*L+l)*D+t];
    sv += b1*v; su += b2*v;
  }
  float partial = sv*wc_w[t] + su*wc_w[D+t];
  #pragma unroll
  for (int off=32; off; off>>=1) partial += __shfl_down(partial, off, 64);
  if ((t&63)==0) red[t>>6] = partial;
  __syncthreads();
  if (t==0) alphaS = sigm(red[0]+red[1]+wc_b[0]);
  __syncthreads();
  float al = alphaS;
  semb[(size_t)b*D+t] = f2bf(ue[(size_t)b*D+t] + al*sv + (1.f-al)*su);
}

// ---- K5: scores = seq_emb(512x128) @ v2e[1:]^T, MFMA bf16, f32 out ----
__global__ __launch_bounds__(256) void k_scores(const unsigned short* __restrict__ A,
                                                const float* __restrict__ v2e,
                                                float* __restrict__ out){
  int tid = threadIdx.x;
  int wv = tid >> 6, lane = tid & 63;
  int q = lane >> 4, r = lane & 15;
  int ntile = blockIdx.x*4 + wv;
  int n = ntile*16 + r;
  bool valid = (ntile < NTILES) && (n < NOUT);
  int brow = valid ? (1 + n) : 0;
  const float* Bf = v2e + (size_t)brow*D + q*8;
  bf16x8 b0, b1, b2, b3;
  #pragma unroll
  for (int j=0;j<8;j++){ b0[j] = (short)f2bf(Bf[j]); b1[j] = (short)f2bf(Bf[32+j]);
                         b2[j] = (short)f2bf(Bf[64+j]); b3[j] = (short)f2bf(Bf[96+j]); }
  #pragma unroll 4
  for (int mt=0; mt<32; mt++){
    const bf16x8* Ap = (const bf16x8*)(A + (size_t)(mt*16 + r)*D + q*8);
    f32x4 acc = {0.f, 0.f, 0.f, 0.f};
    acc = __builtin_amdgcn_mfma_f32_16x16x32_bf16(Ap[0],  b0, acc, 0, 0, 0);
    acc = __builtin_amdgcn_mfma_f32_16x16x32_bf16(Ap[4],  b1, acc, 0, 0, 0);
    acc = __builtin_amdgcn_mfma_f32_16x16x32_bf16(Ap[8],  b2, acc, 0, 0, 0);
    acc = __builtin_amdgcn_mfma_f32_16x16x32_bf16(Ap[12], b3, acc, 0, 0, 0);
    if (valid){
      size_t base = (size_t)(mt*16 + q*4)*NOUT + n;
      out[base]          = acc[0];
      out[base +   NOUT] = acc[1];
      out[base + 2*NOUT] = acc[2];
      out[base + 3*NOUT] = acc[3];
    }
  }
}

extern "C" void kernel_launch(void* const* d_in, const int* in_sizes, int n_in,
                              void* d_out, int out_size, void* d_ws, size_t ws_size,
                              hipStream_t stream) {
  const int* user     = (const int*)d_in[0];
  const int* seq      = (const int*)d_in[1];
  const int* maskp    = (const int*)d_in[2];
  const int* pos_idx  = (const int*)d_in[4];
  const int* esrc     = (const int*)d_in[5];
  const int* edst     = (const int*)d_in[6];
  const int* item_num = (const int*)d_in[7];
  const float* v2e    = (const float*)d_in[8];
  const float* pos_w  = (const float*)d_in[9];
  const float* Wself  = (const float*)d_in[10];
  const float* Wneigh = (const float*)d_in[11];
  const float* bsage  = (const float*)d_in[12];
  const float* w1     = (const float*)d_in[13];
  const float* w2     = (const float*)d_in[14];
  const float* glu1_w = (const float*)d_in[15];
  const float* glu1_b = (const float*)d_in[16];
  const float* glu2_w = (const float*)d_in[17];
  const float* w3     = (const float*)d_in[18];
  const float* w4     = (const float*)d_in[19];
  const float* glu3_w = (const float*)d_in[20];
  const float* glu3_b = (const float*)d_in[21];
  const float* glu4_w = (const float*)d_in[22];
  const float* wc_w   = (const float*)d_in[23];
  const float* wc_b   = (const float*)d_in[24];
  float* out = (float*)d_out;

  // ---- small scratch in d_ws ----
  char* ws = (char*)d_ws;
  size_t off = 0;
  auto take = [&](size_t n){ size_t o = off; off += (n + 255) & ~(size_t)255; return o; };
  size_t o_cnt    = take(16);
  size_t o_scount = take((size_t)MAXS*4);
  size_t o_cursor = take((size_t)MAXS*4);
  size_t zero_end = off;
  size_t o_soffs  = take((size_t)MAXS*4);
  size_t o_invmap = take((size_t)MAXS*4);
  size_t o_beta1  = take((size_t)BS*L*4);
  size_t o_beta2  = take((size_t)BS*L*4);
  size_t o_semb   = take((size_t)BS*D*2);
  int* counters = (int*)(ws + o_cnt);
  int* scount   = (int*)(ws + o_scount);
  int* cursor   = (int*)(ws + o_cursor);
  int* soffs    = (int*)(ws + o_soffs);
  int* invmap   = (int*)(ws + o_invmap);
  float* beta1  = (float*)(ws + o_beta1);
  float* beta2  = (float*)(ws + o_beta2);
  unsigned short* semb = (unsigned short*)(ws + o_semb);

  // ---- big scratch in d_out tail (fully consumed before k_scores writes) ----
  // out = 25,599,488 f32 = 102,397,952 bytes; scratch start 84,000,000 (256-aligned), need ~17.5 MB.
  char* outb = (char*)d_out;
  size_t to = 84000000;
  auto takeT = [&](size_t n){ size_t o = to; to += (n + 255) & ~(size_t)255; return o; };
  int*            map    = (int*)(outb + takeT((size_t)N_NODES*4));
  int*            bucket = (int*)(outb + takeT((size_t)N_EDGES*4));
  float*          neigh  = (float*)(outb + takeT((size_t)MAXS*D*4));
  float*          h1c    = (float*)(outb + takeT((size_t)MAXS*D*4));
  unsigned short* Xcat   = (unsigned short*)(outb + takeT((size_t)BS*L*256*2));
  unsigned short* nh1    = (unsigned short*)(outb + takeT((size_t)BS*L*D*2));
  unsigned short* nh2    = (unsigned short*)(outb + takeT((size_t)BS*L*D*2));
  unsigned short* AU     = (unsigned short*)(outb + takeT((size_t)2*BS*D*2));
  float*          g24    = (float*)(outb + takeT((size_t)2*BS*D*4));
  float*          ie     = (float*)(outb + takeT((size_t)BS*L*D*4));
  float*          ue     = (float*)(outb + takeT((size_t)BS*D*4));
  unsigned short* wT     = (unsigned short*)(outb + takeT((size_t)WT_ELEMS*2));

  hipMemsetAsync(ws, 0, zero_end, stream);
  hipMemsetAsync(map, 0, (size_t)N_NODES*4, stream);

  k_prep<<<448, 256, 0, stream>>>(w1, w3, glu1_w, glu2_w, glu3_w, glu4_w, wT);
  k_mark<<<(MAXS + 255)/256, 256, 0, stream>>>(seq, user, item_num, map);
  k_compact<<<(N_NODES + 255)/256, 256, 0, stream>>>(map, invmap, counters);
  k_count<<<512, 256, 0, stream>>>(edst, map, scount);
  k_scan<<<1, 1024, 0, stream>>>(scount, soffs);
  k_scatter<<<512, 256, 0, stream>>>(esrc, edst, map, soffs, cursor, bucket);
  k_neigh<<<MAXS, D, 0, stream>>>(v2e, bucket, soffs, scount, counters, neigh);
  k_h1<<<(MAXS + SL8 - 1)/SL8, D, 0, stream>>>(v2e, neigh, invmap, counters, Wself, Wneigh, bsage, h1c);
  k4a<<<BS, D, 0, stream>>>(user, seq, maskp, pos_idx, item_num, map, h1c, v2e, pos_w,
                            ie, ue, Xcat, AU);
  k4b<<<BS*L/16, 256, 0, stream>>>(Xcat, wT, nh1, nh2);
  k4c<<<2*BS/16, 256, 0, stream>>>(AU, wT, g24);
  k4d<<<BS*L/16, 256, 0, stream>>>(nh1, nh2, wT, glu1_b, glu3_b, g24, w2, w4, beta1, beta2);
  k4e<<<BS, D, 0, stream>>>(maskp, beta1, beta2, ie, ue, wc_w, wc_b, semb);
  k_scores<<<(NTILES + 3)/4, 256, 0, stream>>>(semb, v2e, out);
}

// Round 6
// 340.527 us; speedup vs baseline: 1.2241x; 1.0093x over previous
//
#include <hip/hip_runtime.h>
#include <hip/hip_bf16.h>

#define N_NODES 50000
#define N_EDGES 600000
#define D 128
#define BS 512
#define L 10
#define MAXS (BS*L + BS)   // 5632 max needed slots
#define NOUT 49999
#define NTILES 3125        // ceil(49999/16)

// wT element offsets (bf16, (n,k) layout)
#define W1T 0        // 128 x 256
#define W3T 32768    // 128 x 128
#define G1T 49152
#define G2T 65536
#define G3T 81920
#define G4T 98304
#define WT_ELEMS 114688

typedef __attribute__((ext_vector_type(8))) short bf16x8;
typedef __attribute__((ext_vector_type(4))) float f32x4;

__device__ __forceinline__ unsigned short f2bf(float f){
  union { float f; unsigned int i; } v; v.f = f;
  unsigned int i = v.i;
  return (unsigned short)((i + 0x7fffu + ((i >> 16) & 1u)) >> 16);
}
__device__ __forceinline__ float sigm(float x){ return 1.f/(1.f+__expf(-x)); }
__device__ __forceinline__ float tanh_f(float x){
  x = fminf(fmaxf(x, -15.f), 15.f);
  float e = __expf(2.f*x);
  return (e-1.f)/(e+1.f);
}

// ---- K1a: mark needed nodes ----
__global__ void k_mark(const int* __restrict__ seq, const int* __restrict__ user,
                       const int* __restrict__ item_num, int* __restrict__ map){
  int i = blockIdx.x*256 + threadIdx.x;
  if (i < BS*L) { map[seq[i]] = 1; }
  else if (i < BS*L + BS) { map[user[i - BS*L] + item_num[0]] = 1; }
}

// ---- K1b: compact to slots; map[n] = slot+2 (0 = unneeded) ----
__global__ void k_compact(int* __restrict__ map, int* __restrict__ invmap, int* __restrict__ counters){
  int n = blockIdx.x*256 + threadIdx.x;
  if (n < N_NODES && map[n]) {
    int s = atomicAdd(&counters[0], 1);
    map[n] = s + 2;
    invmap[s] = n;
  }
}

// ---- K2a: count edges per needed slot ----
__global__ void k_count(const int* __restrict__ edst, const int* __restrict__ map,
                        int* __restrict__ scount){
  for (int e = blockIdx.x*blockDim.x + threadIdx.x; e < N_EDGES; e += gridDim.x*blockDim.x){
    int mv = map[edst[e]];
    if (mv >= 2) atomicAdd(&scount[mv - 2], 1);
  }
}

// ---- K2b: exclusive scan of scount -> soffs ----
__global__ void k_scan(const int* __restrict__ scount, int* __restrict__ soffs){
  __shared__ int part[1024];
  int t = threadIdx.x;
  int base = t*6;
  int loc[6]; int sum = 0;
  #pragma unroll
  for (int j=0;j<6;j++){ int idx = base+j; int c = (idx < MAXS) ? scount[idx] : 0; loc[j]=sum; sum+=c; }
  part[t] = sum; __syncthreads();
  for (int off=1; off<1024; off<<=1){
    int v = (t>=off) ? part[t-off] : 0; __syncthreads();
    part[t] += v; __syncthreads();
  }
  int ex = (t>0) ? part[t-1] : 0;
  #pragma unroll
  for (int j=0;j<6;j++){ int idx = base+j; if (idx < MAXS) soffs[idx] = ex + loc[j]; }
}

// ---- K2c: scatter edge sources into per-slot buckets ----
__global__ void k_scatter(const int* __restrict__ esrc, const int* __restrict__ edst,
                          const int* __restrict__ map, const int* __restrict__ soffs,
                          int* __restrict__ cursor, int* __restrict__ bucket){
  for (int e = blockIdx.x*blockDim.x + threadIdx.x; e < N_EDGES; e += gridDim.x*blockDim.x){
    int mv = map[edst[e]];
    if (mv >= 2){
      int slot = mv - 2;
      int pos = soffs[slot] + atomicAdd(&cursor[slot], 1);
      bucket[pos] = esrc[e];
    }
  }
}

// ---- K2d: per-slot gather-sum -> neigh = agg/max(deg,1) ----
__global__ void k_neigh(const float* __restrict__ v2e, const int* __restrict__ bucket,
                        const int* __restrict__ soffs, const int* __restrict__ scount,
                        const int* __restrict__ counters, float* __restrict__ neigh){
  int s = blockIdx.x; int t = threadIdx.x;
  if (s >= counters[0]) return;
  int cnt = scount[s]; int off = soffs[s];
  float acc = 0.f;
  for (int j=0;j<cnt;j++){
    int src = bucket[off+j];
    acc += v2e[(size_t)src*D + t];
  }
  neigh[(size_t)s*D + t] = acc / fmaxf((float)cnt, 1.0f);
}

// ---- K3: h1 for needed slots only (8 slots/block) ----
#define SL8 8
__global__ __launch_bounds__(128) void k_h1(const float* __restrict__ v2e,
                     const float* __restrict__ neigh, const int* __restrict__ invmap,
                     const int* __restrict__ counters, const float* __restrict__ Wself,
                     const float* __restrict__ Wneigh, const float* __restrict__ bsage,
                     float* __restrict__ h1c){
  __shared__ float vv[SL8][D];
  __shared__ float nn[SL8][D];
  int t = threadIdx.x;
  int nslots = counters[0];
  int sb = blockIdx.x*SL8;
  for (int i=0;i<SL8;i++){
    int s = sb+i;
    if (s < nslots){
      int node = invmap[s];
      vv[i][t] = v2e[(size_t)node*D + t];
      nn[i][t] = neigh[(size_t)s*D + t];
    }
  }
  __syncthreads();
  float bias = bsage[t];
  float acc[SL8];
  #pragma unroll
  for (int i=0;i<SL8;i++) acc[i] = bias;
  for (int k=0;k<D;k++){
    float ws = Wself[k*D + t];
    float wn = Wneigh[k*D + t];
    #pragma unroll
    for (int i=0;i<SL8;i++) acc[i] += vv[i][k]*ws + nn[i][k]*wn;
  }
  for (int i=0;i<SL8;i++){
    int s = sb+i;
    if (s < nslots) h1c[(size_t)s*D + t] = fmaxf(acc[i], 0.f);
  }
}

// ---- K_prep: transpose+cvt weights to bf16 (n,k) layout ----
__global__ __launch_bounds__(256) void k_prep(const float* __restrict__ w1,
    const float* __restrict__ w3, const float* __restrict__ g1,
    const float* __restrict__ g2, const float* __restrict__ g3,
    const float* __restrict__ g4, unsigned short* __restrict__ wT){
  int bid = blockIdx.x, tid = threadIdx.x;
  if (bid < 128){
    int e = bid*256 + tid;
    int k = e >> 7, n = e & 127;
    wT[W1T + n*256 + k] = f2bf(w1[e]);
  } else {
    int mm = (bid - 128) >> 6;
    int e = ((bid - 128) & 63)*256 + tid;
    int k = e >> 7, n = e & 127;
    const float* src = (mm==0)? w3 : (mm==1)? g1 : (mm==2)? g2 : (mm==3)? g3 : g4;
    int dst = (mm==0)? W3T : (mm==1)? G1T : (mm==2)? G2T : (mm==3)? G3T : G4T;
    wT[dst + n*128 + k] = f2bf(src[e]);
  }
}

// ---- K4a: gather ie/pe/ue/avg; build bf16 A-matrices ----
__global__ __launch_bounds__(128) void k4a(const int* __restrict__ user, const int* __restrict__ seq,
    const int* __restrict__ mask, const int* __restrict__ pos_idx, const int* __restrict__ item_num,
    const int* __restrict__ map, const float* __restrict__ h1c, const float* __restrict__ v2e,
    const float* __restrict__ pos_w, float* __restrict__ ie, float* __restrict__ ue,
    unsigned short* __restrict__ Xcat, unsigned short* __restrict__ AU){
  int b = blockIdx.x, t = threadIdx.x;
  float av = 0.f, msum = 0.f;
  for (int l=0;l<L;l++){
    int node = seq[b*L+l];
    int slot = map[node]-2;
    float v = 0.5f*(h1c[(size_t)slot*D+t] + v2e[(size_t)node*D+t]);
    ie[(size_t)(b*L+l)*D+t] = v;
    Xcat[(size_t)(b*L+l)*256 + 128 + t] = f2bf(v);
    int p = pos_idx[b*L+l];
    Xcat[(size_t)(b*L+l)*256 + t] = f2bf(pos_w[(size_t)p*D+t]);
    float m = (float)mask[b*L+l];
    av += v*m; msum += m;
  }
  AU[(size_t)b*D+t] = f2bf(av/msum);
  int unode = user[b]+item_num[0];
  int uslot = map[unode]-2;
  float uv = 0.5f*(h1c[(size_t)uslot*D+t] + v2e[(size_t)unode*D+t]);
  ue[(size_t)b*D+t] = uv;
  AU[(size_t)(512+b)*D+t] = f2bf(uv);
}

// ---- K4bc: blocks 0..319: nh1/nh2 GEMMs. blocks 320..383: g24 GEMM. ----
__global__ __launch_bounds__(256) void k4bc(const unsigned short* __restrict__ Xcat,
    const unsigned short* __restrict__ AU, const unsigned short* __restrict__ wT,
    unsigned short* __restrict__ nh1, unsigned short* __restrict__ nh2,
    float* __restrict__ g24){
  int wv = threadIdx.x>>6, lane = threadIdx.x&63;
  int r = lane&15, q = lane>>4;
  if (blockIdx.x < 320){
    int mt = blockIdx.x;
    const bf16x8* Arow = (const bf16x8*)(Xcat + (size_t)(mt*16+r)*256 + q*8);
    bf16x8 a[8];
    #pragma unroll
    for (int kf=0;kf<8;kf++) a[kf] = Arow[kf*4];
    #pragma unroll
    for (int i=0;i<2;i++){   // nh1, K=256
      int nt = wv + 4*i;
      const bf16x8* Brow = (const bf16x8*)(wT + W1T + (size_t)(nt*16+r)*256 + q*8);
      f32x4 acc = {0.f,0.f,0.f,0.f};
      #pragma unroll
      for (int kf=0;kf<8;kf++)
        acc = __builtin_amdgcn_mfma_f32_16x16x32_bf16(a[kf], Brow[kf*4], acc, 0,0,0);
      #pragma unroll
      for (int g=0; g<4; g++)
        nh1[(size_t)(mt*16 + q*4 + g)*128 + nt*16 + r] = f2bf(tanh_f(acc[g]));
    }
    #pragma unroll
    for (int i=0;i<2;i++){   // nh2, K=128 (ie = Xcat cols 128..255 -> a[4..7])
      int nt = wv + 4*i;
      const bf16x8* Brow = (const bf16x8*)(wT + W3T + (size_t)(nt*16+r)*128 + q*8);
      f32x4 acc = {0.f,0.f,0.f,0.f};
      #pragma unroll
      for (int kf=0;kf<4;kf++)
        acc = __builtin_amdgcn_mfma_f32_16x16x32_bf16(a[4+kf], Brow[kf*4], acc, 0,0,0);
      #pragma unroll
      for (int g=0; g<4; g++)
        nh2[(size_t)(mt*16 + q*4 + g)*128 + nt*16 + r] = f2bf(tanh_f(acc[g]));
    }
  } else {
    int mt = blockIdx.x - 320;  // 0..63
    const unsigned short* Bbase = wT + ((mt*16 >= 512) ? G4T : G2T);
    const bf16x8* Arow = (const bf16x8*)(AU + (size_t)(mt*16+r)*128 + q*8);
    bf16x8 a[4];
    #pragma unroll
    for (int kf=0;kf<4;kf++) a[kf] = Arow[kf*4];
    #pragma unroll
    for (int i=0;i<2;i++){
      int nt = wv + 4*i;
      const bf16x8* Brow = (const bf16x8*)(Bbase + (size_t)(nt*16+r)*128 + q*8);
      f32x4 acc = {0.f,0.f,0.f,0.f};
      #pragma unroll
      for (int kf=0;kf<4;kf++)
        acc = __builtin_amdgcn_mfma_f32_16x16x32_bf16(a[kf], Brow[kf*4], acc, 0,0,0);
      #pragma unroll
      for (int g=0; g<4; g++)
        g24[(size_t)(mt*16 + q*4 + g)*128 + nt*16 + r] = acc[g];
    }
  }
}

// ---- K4d: beta = (sigmoid(nh@glu + b + g) @ w) per row, fused ----
__global__ __launch_bounds__(256) void k4d(const unsigned short* __restrict__ nh1,
    const unsigned short* __restrict__ nh2, const unsigned short* __restrict__ wT,
    const float* __restrict__ glu1_b, const float* __restrict__ glu3_b,
    const float* __restrict__ g24, const float* __restrict__ w2, const float* __restrict__ w4,
    float* __restrict__ beta1, float* __restrict__ beta2){
  __shared__ float sb[4][2][16];
  int mt = blockIdx.x;
  int wv = threadIdx.x>>6, lane = threadIdx.x&63;
  int r = lane&15, q = lane>>4;
  int bidx[4];
  #pragma unroll
  for (int g=0; g<4; g++) bidx[g] = (mt*16 + q*4 + g)/10;
  const bf16x8* A1 = (const bf16x8*)(nh1 + (size_t)(mt*16+r)*128 + q*8);
  const bf16x8* A2 = (const bf16x8*)(nh2 + (size_t)(mt*16+r)*128 + q*8);
  bf16x8 a1[4], a2[4];
  #pragma unroll
  for (int kf=0;kf<4;kf++){ a1[kf] = A1[kf*4]; a2[kf] = A2[kf*4]; }
  float accum0[4] = {0.f,0.f,0.f,0.f};
  float accum1[4] = {0.f,0.f,0.f,0.f};
  #pragma unroll
  for (int i=0;i<2;i++){
    int nt = wv + 4*i;
    int col = nt*16 + r;
    {
      const bf16x8* Brow = (const bf16x8*)(wT + G1T + (size_t)col*128 + q*8);
      f32x4 acc = {0.f,0.f,0.f,0.f};
      #pragma unroll
      for (int kf=0;kf<4;kf++)
        acc = __builtin_amdgcn_mfma_f32_16x16x32_bf16(a1[kf], Brow[kf*4], acc, 0,0,0);
      float gb = glu1_b[col], wc = w2[col];
      #pragma unroll
      for (int g=0; g<4; g++){
        float S = acc[g] + gb + g24[(size_t)bidx[g]*128 + col];
        accum0[g] += sigm(S)*wc;
      }
    }
    {
      const bf16x8* Brow = (const bf16x8*)(wT + G3T + (size_t)col*128 + q*8);
      f32x4 acc = {0.f,0.f,0.f,0.f};
      #pragma unroll
      for (int kf=0;kf<4;kf++)
        acc = __builtin_amdgcn_mfma_f32_16x16x32_bf16(a2[kf], Brow[kf*4], acc, 0,0,0);
      float gb = glu3_b[col], wc = w4[col];
      #pragma unroll
      for (int g=0; g<4; g++){
        float S = acc[g] + gb + g24[(size_t)(512 + bidx[g])*128 + col];
        accum1[g] += sigm(S)*wc;
      }
    }
  }
  #pragma unroll
  for (int g=0; g<4; g++){
    float v0 = accum0[g], v1 = accum1[g];
    v0 += __shfl_xor(v0,1,64); v0 += __shfl_xor(v0,2,64); v0 += __shfl_xor(v0,4,64); v0 += __shfl_xor(v0,8,64);
    v1 += __shfl_xor(v1,1,64); v1 += __shfl_xor(v1,2,64); v1 += __shfl_xor(v1,4,64); v1 += __shfl_xor(v1,8,64);
    accum0[g] = v0; accum1[g] = v1;
  }
  if (r == 0){
    #pragma unroll
    for (int g=0; g<4; g++){
      sb[wv][0][q*4+g] = accum0[g];
      sb[wv][1][q*4+g] = accum1[g];
    }
  }
  __syncthreads();
  if (threadIdx.x < 32){
    int m = threadIdx.x>>4, row = threadIdx.x&15;
    float s = sb[0][m][row]+sb[1][m][row]+sb[2][m][row]+sb[3][m][row];
    if (m) beta2[mt*16+row] = s; else beta1[mt*16+row] = s;
  }
}

// ---- K4e: sess vectors, alpha, seq_emb -> bf16 ----
__global__ __launch_bounds__(128) void k4e(const int* __restrict__ mask,
    const float* __restrict__ beta1, const float* __restrict__ beta2,
    const float* __restrict__ ie, const float* __restrict__ ue,
    const float* __restrict__ wc_w, const float* __restrict__ wc_b,
    unsigned short* __restrict__ semb){
  __shared__ float red[2];
  __shared__ float alphaS;
  int b = blockIdx.x, t = threadIdx.x;
  float sv = 0.f, su = 0.f;
  #pragma unroll
  for (int l=0;l<L;l++){
    float m = (float)mask[b*L+l];
    float b1 = beta1[b*L+l]*m, b2 = beta2[b*L+l]*m;
    float v = ie[(size_t)(b*L+l)*D+t];
    sv += b1*v; su += b2*v;
  }
  float partial = sv*wc_w[t] + su*wc_w[D+t];
  #pragma unroll
  for (int off=32; off; off>>=1) partial += __shfl_down(partial, off, 64);
  if ((t&63)==0) red[t>>6] = partial;
  __syncthreads();
  if (t==0) alphaS = sigm(red[0]+red[1]+wc_b[0]);
  __syncthreads();
  float al = alphaS;
  semb[(size_t)b*D+t] = f2bf(ue[(size_t)b*D+t] + al*sv + (1.f-al)*su);
}

// ---- K5: scores = seq_emb(512x128) @ v2e[1:]^T, MFMA bf16, f32 out ----
// grid (782, 4): blockIdx.y splits the m-loop 4-way -> 3128 blocks, full occupancy.
__global__ __launch_bounds__(256) void k_scores(const unsigned short* __restrict__ A,
                                                const float* __restrict__ v2e,
                                                float* __restrict__ out){
  int tid = threadIdx.x;
  int wv = tid >> 6, lane = tid & 63;
  int q = lane >> 4, r = lane & 15;
  int ntile = blockIdx.x*4 + wv;
  int n = ntile*16 + r;
  bool valid = (ntile < NTILES) && (n < NOUT);
  int brow = valid ? (1 + n) : 0;
  const float* Bf = v2e + (size_t)brow*D + q*8;
  bf16x8 b0, b1, b2, b3;
  #pragma unroll
  for (int j=0;j<8;j++){ b0[j] = (short)f2bf(Bf[j]); b1[j] = (short)f2bf(Bf[32+j]);
                         b2[j] = (short)f2bf(Bf[64+j]); b3[j] = (short)f2bf(Bf[96+j]); }
  int mbase = blockIdx.y*8;
  #pragma unroll
  for (int mi=0; mi<8; mi++){
    int mt = mbase + mi;
    const bf16x8* Ap = (const bf16x8*)(A + (size_t)(mt*16 + r)*D + q*8);
    f32x4 acc = {0.f, 0.f, 0.f, 0.f};
    acc = __builtin_amdgcn_mfma_f32_16x16x32_bf16(Ap[0],  b0, acc, 0, 0, 0);
    acc = __builtin_amdgcn_mfma_f32_16x16x32_bf16(Ap[4],  b1, acc, 0, 0, 0);
    acc = __builtin_amdgcn_mfma_f32_16x16x32_bf16(Ap[8],  b2, acc, 0, 0, 0);
    acc = __builtin_amdgcn_mfma_f32_16x16x32_bf16(Ap[12], b3, acc, 0, 0, 0);
    if (valid){
      size_t base = (size_t)(mt*16 + q*4)*NOUT + n;
      out[base]          = acc[0];
      out[base +   NOUT] = acc[1];
      out[base + 2*NOUT] = acc[2];
      out[base + 3*NOUT] = acc[3];
    }
  }
}

extern "C" void kernel_launch(void* const* d_in, const int* in_sizes, int n_in,
                              void* d_out, int out_size, void* d_ws, size_t ws_size,
                              hipStream_t stream) {
  const int* user     = (const int*)d_in[0];
  const int* seq      = (const int*)d_in[1];
  const int* maskp    = (const int*)d_in[2];
  const int* pos_idx  = (const int*)d_in[4];
  const int* esrc     = (const int*)d_in[5];
  const int* edst     = (const int*)d_in[6];
  const int* item_num = (const int*)d_in[7];
  const float* v2e    = (const float*)d_in[8];
  const float* pos_w  = (const float*)d_in[9];
  const float* Wself  = (const float*)d_in[10];
  const float* Wneigh = (const float*)d_in[11];
  const float* bsage  = (const float*)d_in[12];
  const float* w1     = (const float*)d_in[13];
  const float* w2     = (const float*)d_in[14];
  const float* glu1_w = (const float*)d_in[15];
  const float* glu1_b = (const float*)d_in[16];
  const float* glu2_w = (const float*)d_in[17];
  const float* w3     = (const float*)d_in[18];
  const float* w4     = (const float*)d_in[19];
  const float* glu3_w = (const float*)d_in[20];
  const float* glu3_b = (const float*)d_in[21];
  const float* glu4_w = (const float*)d_in[22];
  const float* wc_w   = (const float*)d_in[23];
  const float* wc_b   = (const float*)d_in[24];
  float* out = (float*)d_out;

  // ---- small scratch in d_ws ----
  char* ws = (char*)d_ws;
  size_t off = 0;
  auto take = [&](size_t n){ size_t o = off; off += (n + 255) & ~(size_t)255; return o; };
  size_t o_cnt    = take(16);
  size_t o_scount = take((size_t)MAXS*4);
  size_t o_cursor = take((size_t)MAXS*4);
  size_t zero_end = off;
  size_t o_soffs  = take((size_t)MAXS*4);
  size_t o_invmap = take((size_t)MAXS*4);
  size_t o_beta1  = take((size_t)BS*L*4);
  size_t o_beta2  = take((size_t)BS*L*4);
  size_t o_semb   = take((size_t)BS*D*2);
  int* counters = (int*)(ws + o_cnt);
  int* scount   = (int*)(ws + o_scount);
  int* cursor   = (int*)(ws + o_cursor);
  int* soffs    = (int*)(ws + o_soffs);
  int* invmap   = (int*)(ws + o_invmap);
  float* beta1  = (float*)(ws + o_beta1);
  float* beta2  = (float*)(ws + o_beta2);
  unsigned short* semb = (unsigned short*)(ws + o_semb);

  // ---- big scratch in d_out tail (fully consumed before k_scores writes) ----
  char* outb = (char*)d_out;
  size_t to = 84000000;
  auto takeT = [&](size_t n){ size_t o = to; to += (n + 255) & ~(size_t)255; return o; };
  int*            map    = (int*)(outb + takeT((size_t)N_NODES*4));
  int*            bucket = (int*)(outb + takeT((size_t)N_EDGES*4));
  float*          neigh  = (float*)(outb + takeT((size_t)MAXS*D*4));
  float*          h1c    = (float*)(outb + takeT((size_t)MAXS*D*4));
  unsigned short* Xcat   = (unsigned short*)(outb + takeT((size_t)BS*L*256*2));
  unsigned short* nh1    = (unsigned short*)(outb + takeT((size_t)BS*L*D*2));
  unsigned short* nh2    = (unsigned short*)(outb + takeT((size_t)BS*L*D*2));
  unsigned short* AU     = (unsigned short*)(outb + takeT((size_t)2*BS*D*2));
  float*          g24    = (float*)(outb + takeT((size_t)2*BS*D*4));
  float*          ie     = (float*)(outb + takeT((size_t)BS*L*D*4));
  float*          ue     = (float*)(outb + takeT((size_t)BS*D*4));
  unsigned short* wT     = (unsigned short*)(outb + takeT((size_t)WT_ELEMS*2));

  hipMemsetAsync(ws, 0, zero_end, stream);
  hipMemsetAsync(map, 0, (size_t)N_NODES*4, stream);

  k_prep<<<448, 256, 0, stream>>>(w1, w3, glu1_w, glu2_w, glu3_w, glu4_w, wT);
  k_mark<<<(MAXS + 255)/256, 256, 0, stream>>>(seq, user, item_num, map);
  k_compact<<<(N_NODES + 255)/256, 256, 0, stream>>>(map, invmap, counters);
  k_count<<<512, 256, 0, stream>>>(edst, map, scount);
  k_scan<<<1, 1024, 0, stream>>>(scount, soffs);
  k_scatter<<<512, 256, 0, stream>>>(esrc, edst, map, soffs, cursor, bucket);
  k_neigh<<<MAXS, D, 0, stream>>>(v2e, bucket, soffs, scount, counters, neigh);
  k_h1<<<(MAXS + SL8 - 1)/SL8, D, 0, stream>>>(v2e, neigh, invmap, counters, Wself, Wneigh, bsage, h1c);
  k4a<<<BS, D, 0, stream>>>(user, seq, maskp, pos_idx, item_num, map, h1c, v2e, pos_w,
                            ie, ue, Xcat, AU);
  k4bc<<<384, 256, 0, stream>>>(Xcat, AU, wT, nh1, nh2, g24);
  k4d<<<BS*L/16, 256, 0, stream>>>(nh1, nh2, wT, glu1_b, glu3_b, g24, w2, w4, beta1, beta2);
  k4e<<<BS, D, 0, stream>>>(maskp, beta1, beta2, ie, ue, wc_w, wc_b, semb);
  k_scores<<<dim3(782, 4), 256, 0, stream>>>(semb, v2e, out);
}